// Round 1
// baseline (294.411 us; speedup 1.0000x reference)
//
#include <hip/hip_runtime.h>

// Problem constants (from reference):
//   D = 8388608 elements, N = M = 1024 (power of two -> mod == AND)
// Outputs concatenated in d_out (float32):
//   [0,      D)      phase_out  (as float)
//   [D,     2D)      mag_out    (as float)
//   [2D,    3D)      signal
//   [3D]             strength   (scalar)
//   [3D+1,  4D+1)    grad_phase   <- base misaligned by 1 float, scalar stores
//   [4D+1,  5D+1)    grad_mag     <- same
constexpr int D_TOTAL = 8388608;
constexpr int TBL = 1024;
constexpr int IDX_MASK = 1023;
constexpr int BLOCK = 256;
constexpr int VEC = 4;                        // elements per thread
constexpr int ELEMS_PER_BLOCK = BLOCK * VEC;  // 1024
constexpr int NBLOCKS = D_TOTAL / ELEMS_PER_BLOCK;  // 8192

__global__ __launch_bounds__(BLOCK) void phasecell_main(
    const int* __restrict__ ctx_p, const int* __restrict__ ctx_m,
    const int* __restrict__ self_p, const int* __restrict__ self_m,
    const float* __restrict__ cos_t, const float* __restrict__ exp_t,
    const float* __restrict__ dcos_t, const float* __restrict__ dexp_t,
    float* __restrict__ out, float* __restrict__ block_sums) {
  // Stage interleaved tables in LDS: one ds_read_b64 per gather.
  __shared__ float2 s_phase[TBL];  // (cos, dcos)
  __shared__ float2 s_mag[TBL];    // (exp, dexp)
  for (int i = threadIdx.x; i < TBL; i += BLOCK) {
    s_phase[i] = make_float2(cos_t[i], dcos_t[i]);
    s_mag[i]   = make_float2(exp_t[i], dexp_t[i]);
  }
  __syncthreads();

  const int base = (blockIdx.x * BLOCK + threadIdx.x) * VEC;

  const int4 cp = *reinterpret_cast<const int4*>(ctx_p + base);
  const int4 cm = *reinterpret_cast<const int4*>(ctx_m + base);
  const int4 sp = *reinterpret_cast<const int4*>(self_p + base);
  const int4 sm = *reinterpret_cast<const int4*>(self_m + base);

  int p[VEC], m[VEC];
  p[0] = (cp.x + sp.x) & IDX_MASK;  m[0] = (cm.x + sm.x) & IDX_MASK;
  p[1] = (cp.y + sp.y) & IDX_MASK;  m[1] = (cm.y + sm.y) & IDX_MASK;
  p[2] = (cp.z + sp.z) & IDX_MASK;  m[2] = (cm.z + sm.z) & IDX_MASK;
  p[3] = (cp.w + sp.w) & IDX_MASK;  m[3] = (cm.w + sm.w) & IDX_MASK;

  float4 po, mo, sig;
  float gph[VEC], gmg[VEC];
  float local = 0.f;
#pragma unroll
  for (int j = 0; j < VEC; ++j) {
    const float2 ph = s_phase[p[j]];
    const float2 mg = s_mag[m[j]];
    const float s = ph.x * mg.x;
    (&sig.x)[j] = s;
    gph[j] = ph.y * mg.x;
    gmg[j] = ph.x * mg.y;
    (&po.x)[j] = (float)p[j];
    (&mo.x)[j] = (float)m[j];
    local += s;
  }

  // Aligned float4 stores (section bases 0, D, 2D are multiples of 4 floats).
  *reinterpret_cast<float4*>(out + base)              = po;
  *reinterpret_cast<float4*>(out + D_TOTAL + base)    = mo;
  *reinterpret_cast<float4*>(out + 2 * D_TOTAL + base) = sig;

  // Grad sections start at 3D+1 / 4D+1 -> 4B misaligned, scalar stores.
  float* gp_base = out + 3 * D_TOTAL + 1 + base;
  float* gm_base = out + 4 * D_TOTAL + 1 + base;
#pragma unroll
  for (int j = 0; j < VEC; ++j) {
    gp_base[j] = gph[j];
    gm_base[j] = gmg[j];
  }

  // Block reduction of `local` -> block_sums[blockIdx.x] (deterministic).
#pragma unroll
  for (int off = 32; off > 0; off >>= 1) local += __shfl_down(local, off, 64);
  __shared__ float wsum[BLOCK / 64];
  const int wave = threadIdx.x >> 6;
  const int lane = threadIdx.x & 63;
  if (lane == 0) wsum[wave] = local;
  __syncthreads();
  if (threadIdx.x == 0) {
    float t = 0.f;
#pragma unroll
    for (int w = 0; w < BLOCK / 64; ++w) t += wsum[w];
    block_sums[blockIdx.x] = t;
  }
}

__global__ __launch_bounds__(BLOCK) void phasecell_reduce(
    const float* __restrict__ partials, float* __restrict__ strength_out) {
  float s = 0.f;
  for (int i = threadIdx.x; i < NBLOCKS; i += BLOCK) s += partials[i];
#pragma unroll
  for (int off = 32; off > 0; off >>= 1) s += __shfl_down(s, off, 64);
  __shared__ float wsum[BLOCK / 64];
  const int wave = threadIdx.x >> 6;
  const int lane = threadIdx.x & 63;
  if (lane == 0) wsum[wave] = s;
  __syncthreads();
  if (threadIdx.x == 0) {
    float t = 0.f;
#pragma unroll
    for (int w = 0; w < BLOCK / 64; ++w) t += wsum[w];
    strength_out[0] = t;  // out[3D]
  }
}

extern "C" void kernel_launch(void* const* d_in, const int* in_sizes, int n_in,
                              void* d_out, int out_size, void* d_ws, size_t ws_size,
                              hipStream_t stream) {
  const int* ctx_p  = (const int*)d_in[0];
  const int* ctx_m  = (const int*)d_in[1];
  const int* self_p = (const int*)d_in[2];
  const int* self_m = (const int*)d_in[3];
  const float* cos_t  = (const float*)d_in[4];
  const float* exp_t  = (const float*)d_in[5];
  const float* dcos_t = (const float*)d_in[6];
  const float* dexp_t = (const float*)d_in[7];
  float* out = (float*)d_out;
  float* block_sums = (float*)d_ws;  // NBLOCKS floats = 32 KB

  phasecell_main<<<NBLOCKS, BLOCK, 0, stream>>>(
      ctx_p, ctx_m, self_p, self_m, cos_t, exp_t, dcos_t, dexp_t, out, block_sums);
  phasecell_reduce<<<1, BLOCK, 0, stream>>>(block_sums, out + 3 * (size_t)D_TOTAL);
}